// Round 4
// baseline (200.823 us; speedup 1.0000x reference)
//
#include <hip/hip_runtime.h>

#define L_IN    4000
#define CIN     512
#define KSZ     16
#define LOUT    31992   // 8 * 3999
#define NQ      3999    // valid q: 0..3998
#define QPB     128     // q positions per block (2 per thread, strided by 64)
#define RSTRIDE 1152    // per-wave reduction stride in floats (9*127+8 = 1151)

// Block = (b, 128-q tile), 512 threads = 8 waves; wave w owns ci [w*64, w*64+64).
// Thread: lane computes Q=2 q-positions (q0 + lane, q0 + 64 + lane), 8 taps each.
// Grid = 32 x 16 = 512 blocks -> 2 blocks/CU, 16 waves/CU (4/SIMD) for latency
// hiding (R3's 8 waves/CU was the binding constraint, not LDS traffic).
// Weights staged once to LDS (32 KB), wave-uniform ds_read_b128 broadcasts;
// LDS reused for the cross-wave (ci) reduction with stride-9 padding (36 KB).
__global__ __launch_bounds__(512, 4)
void dereverb_kernel(const float* __restrict__ x,
                     const float* __restrict__ t60s,
                     const float* __restrict__ kw,
                     float* __restrict__ out)
{
    __shared__ float lds[8 * RSTRIDE];   // 36 KB (>= 32 KB weight staging)

    const int b    = blockIdx.y;
    const int q0   = blockIdx.x * QPB;
    const int tid  = threadIdx.x;
    const int lane = tid & 63;
    const int wave = tid >> 6;

    // Per-sample kernel index (uniform): jnp.round = RNE = rintf.
    float t60 = t60s[b & 7];
    int kidx = (int)rintf(t60 * 100.0f) - 10;
    kidx = __builtin_amdgcn_readfirstlane(kidx);
    const float4* wsrc = (const float4*)(kw + (size_t)kidx * (CIN * KSZ));

    // Stage all 512x16 weights: 2048 float4 / 512 threads = 4 each, coalesced.
    #pragma unroll
    for (int i = 0; i < 4; ++i)
        ((float4*)lds)[tid + i * 512] = wsrc[tid + i * 512];
    __syncthreads();

    // Two q positions per thread; clamp loads in-bounds (q=3998 last valid;
    // loads touch qc and qc+1 <= 3999).
    const int qa = q0 + lane;
    const int qb = q0 + 64 + lane;
    const int qca = qa < NQ - 1 ? qa : (NQ - 1);
    const int qcb = qb < NQ - 1 ? qb : (NQ - 1);

    const float* xb = x + ((size_t)b * CIN + wave * 64) * L_IN;
    const float* xpa = xb + qca;
    const float* xpb = xb + qcb;

    const float4* wl = (const float4*)(lds + wave * 64 * KSZ);

    float acc[2][8];
    #pragma unroll
    for (int qi = 0; qi < 2; ++qi)
        #pragma unroll
        for (int r = 0; r < 8; ++r) acc[qi][r] = 0.0f;

    #pragma unroll 4
    for (int ci = 0; ci < 64; ++ci) {
        float a0 = xpa[0], a1 = xpa[1];   // x[b, ci, qa], x[b, ci, qa+1]
        float b0 = xpb[0], b1 = xpb[1];
        xpa += L_IN;
        xpb += L_IN;
        float4 wv[4];
        wv[0] = wl[0];                    // wave-uniform ds_read_b128 -> broadcast
        wv[1] = wl[1];
        wv[2] = wl[2];
        wv[3] = wl[3];
        wl += 4;
        const float* wf = (const float*)wv;
        #pragma unroll
        for (int r = 0; r < 8; ++r) {
            acc[0][r] = fmaf(a1, wf[r],     acc[0][r]);
            acc[0][r] = fmaf(a0, wf[r + 8], acc[0][r]);
            acc[1][r] = fmaf(b1, wf[r],     acc[1][r]);
            acc[1][r] = fmaf(b0, wf[r + 8], acc[1][r]);
        }
    }

    // Clamped lanes (q > 3998) contribute nothing.
    if (qa > NQ - 1)
        #pragma unroll
        for (int r = 0; r < 8; ++r) acc[0][r] = 0.0f;
    if (qb > NQ - 1)
        #pragma unroll
        for (int r = 0; r < 8; ++r) acc[1][r] = 0.0f;

    // Cross-wave (ci) reduction. Layout: lds[wave*RSTRIDE + 9*ql + r].
    __syncthreads();   // weight reads done; safe to overwrite
    #pragma unroll
    for (int qi = 0; qi < 2; ++qi) {
        int ql = qi * 64 + lane;
        float* rp = lds + wave * RSTRIDE + 9 * ql;
        #pragma unroll
        for (int r = 0; r < 8; ++r) rp[r] = acc[qi][r];
    }
    __syncthreads();

    // Epilogue: 1024 outputs / 512 threads = 2 each (float2, coalesced).
    const size_t ob = (size_t)b * LOUT + (size_t)q0 * 8;
    const int tl = tid * 2;
    if (q0 * 8 + tl < LOUT) {            // cutoff even -> pair never straddles
        int ql = tl >> 3, r = tl & 7;    // r even; r+1 in same ql row
        float s0 = 0.0f, s1 = 0.0f;
        #pragma unroll
        for (int w = 0; w < 8; ++w) {
            s0 += lds[w * RSTRIDE + 9 * ql + r];
            s1 += lds[w * RSTRIDE + 9 * ql + r + 1];
        }
        *(float2*)(out + ob + tl) = make_float2(s0, s1);
    }
}

extern "C" void kernel_launch(void* const* d_in, const int* in_sizes, int n_in,
                              void* d_out, int out_size, void* d_ws, size_t ws_size,
                              hipStream_t stream) {
    const float* x    = (const float*)d_in[0];   // (16, 512, 4000)
    const float* t60s = (const float*)d_in[1];   // (8,)
    const float* kw   = (const float*)d_in[2];   // (41, 512, 1, 16)
    float* out = (float*)d_out;                  // (16, 1, 31992)

    dim3 grid((NQ + QPB - 1) / QPB, 16);         // (32, 16)
    dereverb_kernel<<<grid, 512, 0, stream>>>(x, t60s, kw, out);
}

// Round 5
// 195.557 us; speedup vs baseline: 1.0269x; 1.0269x over previous
//
#include <hip/hip_runtime.h>

#define L_IN   4000
#define CIN    512
#define KSZ    16
#define LOUT   31992   // 8 * 3999
#define NQ     3999    // valid q: 0..3998
#define QPB    256     // q positions per block (4 per thread, strided by 64)
#define RST    1152    // reduction region stride (9*127 + 8 + 1), floats

// Block = (b, 256-q tile), 1024 threads = 16 waves; wave w owns ci [w*32, w*32+32).
// Thread: Q=4 q-positions (q0 + qi*64 + lane), 8 taps each -> 32 accumulators.
// Grid 16x16 = 256 blocks = 1 block/CU -> 16 waves/CU (4/SIMD).
// Per-CU LDS cost: 16 waves x 32 ci x 4 ds_read_b128 ~ 10 us < HBM floor (~20 us);
// this fixes R2 (LDS-bound: 128 ci/wave) and R3 (latency-bound: 2 waves/SIMD).
// 16-wave reduction in two qi-half passes through 36 KB padded LDS (64 KB limit).
__global__ __launch_bounds__(1024, 4)
void dereverb_kernel(const float* __restrict__ x,
                     const float* __restrict__ t60s,
                     const float* __restrict__ kw,
                     float* __restrict__ out)
{
    __shared__ float lds[8 * RST];   // 36 KB: weights (32 KB), then reduction

    const int b    = blockIdx.y;
    const int q0   = blockIdx.x * QPB;
    const int tid  = threadIdx.x;
    const int lane = tid & 63;
    const int wave = tid >> 6;

    // Per-sample kernel index (uniform): jnp.round = RNE = rintf.
    float t60 = t60s[b & 7];
    int kidx = (int)rintf(t60 * 100.0f) - 10;
    kidx = __builtin_amdgcn_readfirstlane(kidx);
    const float4* wsrc = (const float4*)(kw + (size_t)kidx * (CIN * KSZ));

    // Stage all 512x16 weights: 2048 float4 / 1024 threads = 2 each, coalesced.
    ((float4*)lds)[tid]        = wsrc[tid];
    ((float4*)lds)[tid + 1024] = wsrc[tid + 1024];
    __syncthreads();

    // 4 q positions per thread; clamp loads in-bounds (q=3998 last valid;
    // loads touch qc and qc+1 <= 3999).
    const float* xb = x + ((size_t)b * CIN + wave * 32) * L_IN;
    const float* xp[4];
    #pragma unroll
    for (int qi = 0; qi < 4; ++qi) {
        int q  = q0 + qi * 64 + lane;
        int qc = q < NQ - 1 ? q : (NQ - 1);
        xp[qi] = xb + qc;
    }

    const float4* wl = (const float4*)(lds + wave * 32 * KSZ);

    float acc[4][8];
    #pragma unroll
    for (int qi = 0; qi < 4; ++qi)
        #pragma unroll
        for (int r = 0; r < 8; ++r) acc[qi][r] = 0.0f;

    #pragma unroll 4
    for (int ci = 0; ci < 32; ++ci) {
        float x0[4], x1[4];
        #pragma unroll
        for (int qi = 0; qi < 4; ++qi) {
            x0[qi] = xp[qi][0];      // x[b, ci, q]
            x1[qi] = xp[qi][1];      // x[b, ci, q+1]
            xp[qi] += L_IN;
        }
        float4 wv[4];
        wv[0] = wl[0];               // wave-uniform ds_read_b128 -> broadcast
        wv[1] = wl[1];
        wv[2] = wl[2];
        wv[3] = wl[3];
        wl += 4;
        const float* wf = (const float*)wv;
        #pragma unroll
        for (int qi = 0; qi < 4; ++qi)
            #pragma unroll
            for (int r = 0; r < 8; ++r) {
                acc[qi][r] = fmaf(x1[qi], wf[r],     acc[qi][r]);
                acc[qi][r] = fmaf(x0[qi], wf[r + 8], acc[qi][r]);
            }
    }

    // Clamped lanes (q > 3998) contribute nothing.
    #pragma unroll
    for (int qi = 0; qi < 4; ++qi)
        if (q0 + qi * 64 + lane > NQ - 1)
            #pragma unroll
            for (int r = 0; r < 8; ++r) acc[qi][r] = 0.0f;

    // 16-wave reduction, two passes over qi-halves. Region w: 128 ql x 8 r,
    // addr = w*RST + 9*ql + r (stride 9: lane stores 2-way/free, reads clean).
    const size_t obase = (size_t)b * LOUT + (size_t)q0 * 8;
    #pragma unroll
    for (int p = 0; p < 2; ++p) {
        __syncthreads();                 // weights done / previous pass done
        if (wave >= 8) {                 // waves 8..15 store region (wave-8)
            #pragma unroll
            for (int h = 0; h < 2; ++h) {
                float* rp = lds + (wave - 8) * RST + 9 * (h * 64 + lane);
                #pragma unroll
                for (int r = 0; r < 8; ++r) rp[r] = acc[2 * p + h][r];
            }
        }
        __syncthreads();
        if (wave < 8) {                  // waves 0..7 fold into region wave
            #pragma unroll
            for (int h = 0; h < 2; ++h) {
                float* rp = lds + wave * RST + 9 * (h * 64 + lane);
                #pragma unroll
                for (int r = 0; r < 8; ++r) rp[r] += acc[2 * p + h][r];
            }
        }
        __syncthreads();
        // 1024 outputs this pass, one per thread, coalesced dword stores.
        int tl = p * 1024 + tid;         // t = q0*8 + tl
        if (q0 * 8 + tl < LOUT) {        // only last q-tile trims
            int ql = tid >> 3, r = tid & 7;
            float s = 0.0f;
            #pragma unroll
            for (int w = 0; w < 8; ++w)
                s += lds[w * RST + 9 * ql + r];
            out[obase + tl] = s;
        }
    }
}

extern "C" void kernel_launch(void* const* d_in, const int* in_sizes, int n_in,
                              void* d_out, int out_size, void* d_ws, size_t ws_size,
                              hipStream_t stream) {
    const float* x    = (const float*)d_in[0];   // (16, 512, 4000)
    const float* t60s = (const float*)d_in[1];   // (8,)
    const float* kw   = (const float*)d_in[2];   // (41, 512, 1, 16)
    float* out = (float*)d_out;                  // (16, 1, 31992)

    dim3 grid((NQ + QPB - 1) / QPB, 16);         // (16, 16)
    dereverb_kernel<<<grid, 1024, 0, stream>>>(x, t60s, kw, out);
}

// Round 6
// 190.386 us; speedup vs baseline: 1.0548x; 1.0272x over previous
//
#include <hip/hip_runtime.h>

#define L_IN   4000
#define CIN    512
#define KSZ    16
#define LOUT   31992   // 8 * 3999
#define NQ     3999    // valid q: 0..3998
#define QPB    256     // q positions per block (4 contiguous per thread)
#define RST    1088    // reduction region stride: 64 lanes * 17 floats

// Block = (b, 256-q tile), 1024 threads = 16 waves; wave w owns ci [w*32, w*32+32).
// Thread: 4 CONTIGUOUS q's (qb = q0 + 4*lane) -> per (wave,ci) the x-load is one
// 1 KB contiguous float4 burst (a full HBM page) instead of R2-R5's scattered
// 256 B bursts at 16 KB stride (the config-invariant ~2.3 TB/s wall).
// Halo x[q+1] for qi=3 comes from a stride-4 dword load (L1/L2-hit).
// Weights staged once to LDS, wave-uniform ds_read_b128 broadcast.
// 16-wave reduction: two qi-half passes, per-lane 17-padded chunks (skewed,
// bank-balanced); 34 KB LDS total, unioned with the 32 KB weight stage.
__global__ __launch_bounds__(1024, 4)
void dereverb_kernel(const float* __restrict__ x,
                     const float* __restrict__ t60s,
                     const float* __restrict__ kw,
                     float* __restrict__ out)
{
    __shared__ float lds[8 * RST];   // 34 KB

    const int b    = blockIdx.y;
    const int q0   = blockIdx.x * QPB;
    const int tid  = threadIdx.x;
    const int lane = tid & 63;
    const int wave = tid >> 6;

    // Per-sample kernel index (uniform): jnp.round = RNE = rintf.
    float t60 = t60s[b & 7];
    int kidx = (int)rintf(t60 * 100.0f) - 10;
    kidx = __builtin_amdgcn_readfirstlane(kidx);
    const float4* wsrc = (const float4*)(kw + (size_t)kidx * (CIN * KSZ));

    // Stage all 512x16 weights: 2048 float4 / 1024 threads = 2 each, coalesced.
    ((float4*)lds)[tid]        = wsrc[tid];
    ((float4*)lds)[tid + 1024] = wsrc[tid + 1024];
    __syncthreads();

    // Lane's q base; clamp keeps all loads inside the current row:
    //  - float4 at qbl: qbl <= 3996 -> reads x[3996..3999], in-bounds
    //  - halo dword at qan = min(qb+4, 3999), in-bounds
    // Lanes/q's past 3998 produce garbage that is zeroed before reduction.
    const int qb  = q0 + 4 * lane;
    const int qbl = qb < 3996 ? qb : 3996;          // multiple of 4 -> 16B aligned
    const int qan = (qb + 4) < NQ ? (qb + 4) : NQ;  // min(qb+4, 3999)

    const float* xr = x + ((size_t)b * CIN + wave * 32) * L_IN;
    const float* xp = xr + qbl;
    const float* xq = xr + qan;

    const float4* wl = (const float4*)(lds + wave * 32 * KSZ);

    float acc[4][8];
    #pragma unroll
    for (int qi = 0; qi < 4; ++qi)
        #pragma unroll
        for (int r = 0; r < 8; ++r) acc[qi][r] = 0.0f;

    #pragma unroll 4
    for (int ci = 0; ci < 32; ++ci) {
        float4 a  = *(const float4*)xp;   // x[q .. q+3], 1 KB/wave contiguous
        float  an = *xq;                  // x[q+4] halo (cache-hit)
        xp += L_IN;
        xq += L_IN;

        float4 wv[4];
        wv[0] = wl[0];                    // wave-uniform ds_read_b128 -> broadcast
        wv[1] = wl[1];
        wv[2] = wl[2];
        wv[3] = wl[3];
        wl += 4;
        const float* wf = (const float*)wv;

        const float x0v[4] = {a.x, a.y, a.z, a.w};
        const float x1v[4] = {a.y, a.z, a.w, an};
        #pragma unroll
        for (int qi = 0; qi < 4; ++qi)
            #pragma unroll
            for (int r = 0; r < 8; ++r) {
                acc[qi][r] = fmaf(x1v[qi], wf[r],     acc[qi][r]);
                acc[qi][r] = fmaf(x0v[qi], wf[r + 8], acc[qi][r]);
            }
    }

    // Zero contributions from invalid q (> 3998) / clamped lanes.
    #pragma unroll
    for (int qi = 0; qi < 4; ++qi)
        if (qb + qi > NQ - 1)
            #pragma unroll
            for (int r = 0; r < 8; ++r) acc[qi][r] = 0.0f;

    // 16-wave reduction in two passes over qi-halves (qi = 2p+qih).
    // Region w layout: addr = w*RST + lane*17 + qih*8 + r  (17-padded chunk:
    // b128 stores are perfectly bank-balanced; epilogue reads <=3-way).
    const size_t obase = (size_t)b * LOUT + (size_t)q0 * 8;
    #pragma unroll
    for (int p = 0; p < 2; ++p) {
        __syncthreads();                 // weights / previous pass reads done
        if (wave >= 8) {                 // waves 8..15 store region (wave-8)
            float* rp = lds + (wave - 8) * RST + lane * 17;
            #pragma unroll
            for (int qih = 0; qih < 2; ++qih)
                #pragma unroll
                for (int r = 0; r < 8; ++r)
                    rp[qih * 8 + r] = acc[2 * p + qih][r];
        }
        __syncthreads();
        if (wave < 8) {                  // waves 0..7 fold into region wave
            float* rp = lds + wave * RST + lane * 17;
            #pragma unroll
            for (int qih = 0; qih < 2; ++qih)
                #pragma unroll
                for (int r = 0; r < 8; ++r)
                    rp[qih * 8 + r] += acc[2 * p + qih][r];
        }
        __syncthreads();
        // Pass p covers, per compute-lane k, the 16 outputs t_local =
        // 32k + 16p + j  (j = qih*8 + r). 1024 outputs/pass, one per thread.
        int k = tid >> 4, j = tid & 15;
        int tl = 32 * k + 16 * p + j;
        if (q0 * 8 + tl < LOUT) {        // only the last q-tile trims
            float s = 0.0f;
            #pragma unroll
            for (int w = 0; w < 8; ++w)
                s += lds[w * RST + k * 17 + j];
            out[obase + tl] = s;
        }
    }
}

extern "C" void kernel_launch(void* const* d_in, const int* in_sizes, int n_in,
                              void* d_out, int out_size, void* d_ws, size_t ws_size,
                              hipStream_t stream) {
    const float* x    = (const float*)d_in[0];   // (16, 512, 4000)
    const float* t60s = (const float*)d_in[1];   // (8,)
    const float* kw   = (const float*)d_in[2];   // (41, 512, 1, 16)
    float* out = (float*)d_out;                  // (16, 1, 31992)

    dim3 grid((NQ + QPB - 1) / QPB, 16);         // (16, 16)
    dereverb_kernel<<<grid, 1024, 0, stream>>>(x, t60s, kw, out);
}